// Round 1
// baseline (115.783 us; speedup 1.0000x reference)
//
#include <hip/hip_runtime.h>
#include <math.h>

#define Hh 72
#define Ww 128
#define HW (Hh*Ww)          // 9216 grid points
#define NP 24               // points per curve
#define Mp 40               // pred curves
#define Ng 24               // gt curves
#define Bb 2                // batch
#define NRS 64
#define THICKc 0.03f
#define SHARPc 80.0f

// ---------------------------------------------------------------------------
// K1: prepare gt mask + arclength resample (both pred and gt) to NRS points.
// One block per curve, 64 threads (one per resample point).
// ---------------------------------------------------------------------------
__global__ __launch_bounds__(64) void k_resample(
    const float* __restrict__ pred,   // B*M*NP*2
    const float* __restrict__ gt,     // B*N*NP*2
    const float* __restrict__ vis,    // B*N*NP
    float* __restrict__ predRS,       // B*M*NRS*2
    float* __restrict__ gtRS,         // B*N*NRS*2
    float* __restrict__ gtPM)         // B*N*NP
{
    int blk = blockIdx.x;             // 0 .. B*(M+N)-1
    int b = blk / (Mp + Ng);
    int c = blk % (Mp + Ng);
    bool isPred = (c < Mp);
    int tid = threadIdx.x;

    __shared__ float qx[NP], qy[NP], pm[NP], cum[NP];
    __shared__ float s_total;

    const float* src = isPred ? pred + (size_t)(b * Mp + c) * NP * 2
                              : gt   + (size_t)(b * Ng + (c - Mp)) * NP * 2;
    if (tid < NP) {
        qx[tid] = src[tid * 2 + 0];
        qy[tid] = src[tid * 2 + 1];
        pm[tid] = isPred ? 1.0f
                         : ((vis[(b * Ng + (c - Mp)) * NP + tid] > 0.5f) ? 1.0f : 0.0f);
    }
    __syncthreads();
    if (tid == 0) {
        if (!isPred) {
            float s = 0.0f;
            for (int p = 0; p < NP; p++) s += pm[p];
            if (s < 2.0f)                       // fallback: fewer than 2 visible
                for (int p = 0; p < NP; p++) pm[p] = 1.0f;
        }
        float acc = 0.0f;
        cum[0] = 0.0f;
        for (int s = 0; s < NP - 1; s++) {
            float dx = qx[s + 1] - qx[s], dy = qy[s + 1] - qy[s];
            float sl = sqrtf(dx * dx + dy * dy) * (pm[s] * pm[s + 1]);
            acc += sl;
            cum[s + 1] = acc;
        }
        s_total = acc;
    }
    __syncthreads();
    if (!isPred && tid < NP) gtPM[(b * Ng + (c - Mp)) * NP + tid] = pm[tid];

    float total = s_total;
    float t = ((float)tid / 63.0f) * total;
    // searchsorted(cum, t, side='right') - 1  == count(cum <= t) - 1
    int cnt = 0;
    for (int p = 0; p < NP; p++) cnt += (cum[p] <= t) ? 1 : 0;
    int idx = cnt - 1;
    idx = (idx < 0) ? 0 : ((idx > NP - 2) ? NP - 2 : idx);
    float lt = cum[idx], rt = cum[idx + 1];
    float alpha = (t - lt) / fmaxf(rt - lt, 1e-8f);
    float ox = qx[idx] + alpha * (qx[idx + 1] - qx[idx]);
    float oy = qy[idx] + alpha * (qy[idx + 1] - qy[idx]);
    if (total < 1e-8f) { ox = qx[0]; oy = qy[0]; }   // degenerate curve
    float* dst = isPred ? predRS + (size_t)(b * Mp + c) * NRS * 2
                        : gtRS   + (size_t)(b * Ng + (c - Mp)) * NRS * 2;
    dst[tid * 2 + 0] = ox;
    dst[tid * 2 + 1] = oy;
}

// ---------------------------------------------------------------------------
// K2: soft occupancy masks on the ORIGINAL 24-pt polylines.
// grid = (HW/256, B*(M+N)); block handles 256 grid points of one curve.
// ---------------------------------------------------------------------------
__global__ __launch_bounds__(256) void k_softmask(
    const float* __restrict__ pred,
    const float* __restrict__ gt,
    const float* __restrict__ gtPM,
    float* __restrict__ pmask,        // B*M*HW
    float* __restrict__ gmask)        // B*N*HW
{
    int c = blockIdx.y;               // 0 .. B*(M+N)-1
    int b = c / (Mp + Ng);
    int cc = c % (Mp + Ng);
    bool isPred = (cc < Mp);
    int g = blockIdx.x * blockDim.x + threadIdx.x;

    __shared__ float qx[NP], qy[NP], pm[NP];
    if (threadIdx.x < NP) {
        const float* src = isPred ? pred + (size_t)(b * Mp + cc) * NP * 2
                                  : gt   + (size_t)(b * Ng + (cc - Mp)) * NP * 2;
        qx[threadIdx.x] = src[threadIdx.x * 2 + 0];
        qy[threadIdx.x] = src[threadIdx.x * 2 + 1];
        pm[threadIdx.x] = isPred ? 1.0f : gtPM[(b * Ng + (cc - Mp)) * NP + threadIdx.x];
    }
    __syncthreads();

    float gx = (float)(g % Ww) * (1.0f / 127.0f);
    float gy = (float)(g / Ww) * (1.0f / 71.0f);

    float best2 = 1e30f;
    bool anyValid = false;
    for (int s = 0; s < NP - 1; s++) {
        if (pm[s] * pm[s + 1] > 0.5f) {          // wave-uniform branch (pm is per-curve)
            anyValid = true;
            float ax = qx[s], ay = qy[s];
            float abx = qx[s + 1] - ax, aby = qy[s + 1] - ay;
            float denom = fmaxf(abx * abx + aby * aby, 1e-8f);
            float t = ((gx - ax) * abx + (gy - ay) * aby) / denom;
            t = fminf(fmaxf(t, 0.0f), 1.0f);
            float dx = gx - (ax + t * abx), dy = gy - (ay + t * aby);
            best2 = fminf(best2, dx * dx + dy * dy);
        }
    }
    float mind;
    if (anyValid) {
        mind = sqrtf(best2);
    } else {
        float b2 = 1e30f;
        for (int p = 0; p < NP; p++) {
            if (pm[p] > 0.5f) {
                float dx = gx - qx[p], dy = gy - qy[p];
                b2 = fminf(b2, dx * dx + dy * dy);
            }
        }
        mind = sqrtf(b2);
    }
    float x = (THICKc - mind) * SHARPc;
    float mval = 1.0f / (1.0f + expf(-x));
    if (isPred) pmask[(size_t)(b * Mp + cc) * HW + g] = mval;
    else        gmask[(size_t)(b * Ng + (cc - Mp)) * HW + g] = mval;
}

// ---------------------------------------------------------------------------
// K3: per-(b,i,j) pair cost. 256 threads: all do the overlap grid reduction;
// threads 0..63 do Chamfer/tangent; 0..61 do curvature. Block-reduce, write.
// ---------------------------------------------------------------------------
__device__ __forceinline__ float block_reduce_sum(float v, float* red, int tid) {
    red[tid] = v;
    __syncthreads();
    for (int s = 128; s > 0; s >>= 1) {
        if (tid < s) red[tid] += red[tid + s];
        __syncthreads();
    }
    float r = red[0];
    __syncthreads();
    return r;
}

__global__ __launch_bounds__(256) void k_cost(
    const float* __restrict__ predRS,
    const float* __restrict__ gtRS,
    const float* __restrict__ pmask,
    const float* __restrict__ gmask,
    const float* __restrict__ gtExist,   // B*N
    float* __restrict__ out)             // B*M*N
{
    int pair = blockIdx.x;               // B*M*N
    int j = pair % Ng;
    int i = (pair / Ng) % Mp;
    int b = pair / (Ng * Mp);
    int tid = threadIdx.x;

    __shared__ float px[NRS], py[NRS], gxr[NRS], gyr[NRS];
    __shared__ float red[256];

    if (tid < NRS) {
        px[tid]  = predRS[((size_t)(b * Mp + i) * NRS + tid) * 2 + 0];
        py[tid]  = predRS[((size_t)(b * Mp + i) * NRS + tid) * 2 + 1];
        gxr[tid] = gtRS[((size_t)(b * Ng + j) * NRS + tid) * 2 + 0];
        gyr[tid] = gtRS[((size_t)(b * Ng + j) * NRS + tid) * 2 + 1];
    }
    __syncthreads();

    // ---- overlap: sums of min/max over the 9216-pt grid ----
    const float* pmk = pmask + (size_t)(b * Mp + i) * HW;
    const float* gmk = gmask + (size_t)(b * Ng + j) * HW;
    float smin = 0.0f, smax = 0.0f;
    for (int g = tid; g < HW; g += 256) {
        float p = pmk[g], q = gmk[g];
        smin += fminf(p, q);
        smax += fmaxf(p, q);
    }

    float symv = 0.0f, tanv = 0.0f, curvv = 0.0f;
    if (tid < NRS) {
        // Chamfer: pred point tid -> gt polyline
        float p0x = px[tid], p0y = py[tid];
        float bst = 1e30f;
        for (int s = 0; s < NRS - 1; s++) {
            float ax = gxr[s], ay = gyr[s];
            float abx = gxr[s + 1] - ax, aby = gyr[s + 1] - ay;
            float denom = fmaxf(abx * abx + aby * aby, 1e-8f);
            float t = ((p0x - ax) * abx + (p0y - ay) * aby) / denom;
            t = fminf(fmaxf(t, 0.0f), 1.0f);
            float dx = p0x - (ax + t * abx), dy = p0y - (ay + t * aby);
            bst = fminf(bst, dx * dx + dy * dy);
        }
        float dpg = sqrtf(bst);
        // gt point tid -> pred polyline
        float q0x = gxr[tid], q0y = gyr[tid];
        bst = 1e30f;
        for (int s = 0; s < NRS - 1; s++) {
            float ax = px[s], ay = py[s];
            float abx = px[s + 1] - ax, aby = py[s + 1] - ay;
            float denom = fmaxf(abx * abx + aby * aby, 1e-8f);
            float t = ((q0x - ax) * abx + (q0y - ay) * aby) / denom;
            t = fminf(fmaxf(t, 0.0f), 1.0f);
            float dx = q0x - (ax + t * abx), dy = q0y - (ay + t * aby);
            bst = fminf(bst, dx * dx + dy * dy);
        }
        float dgp = sqrtf(bst);
        symv = 0.5f * (dpg + dgp);

        // tangent alignment
        int kp = (tid == NRS - 1) ? NRS - 1 : tid + 1;
        int km = (tid == 0) ? 0 : tid - 1;
        float tx = px[kp] - px[km], ty = py[kp] - py[km];
        float nrm = fmaxf(sqrtf(tx * tx + ty * ty), 1e-8f);
        tx /= nrm; ty /= nrm;
        float gtx = gxr[kp] - gxr[km], gty = gyr[kp] - gyr[km];
        float nrm2 = fmaxf(sqrtf(gtx * gtx + gty * gty), 1e-8f);
        gtx /= nrm2; gty /= nrm2;
        tanv = fabsf(tx * gtx + ty * gty);

        // curvature (second differences), threads 0..61
        if (tid < NRS - 2) {
            float psx = px[tid + 2] - 2.0f * px[tid + 1] + px[tid];
            float psy = py[tid + 2] - 2.0f * py[tid + 1] + py[tid];
            float gsx = gxr[tid + 2] - 2.0f * gxr[tid + 1] + gxr[tid];
            float gsy = gyr[tid + 2] - 2.0f * gyr[tid + 1] + gyr[tid];
            float d1 = fabsf(psx - gsx);
            float d2 = fabsf(psy - gsy);
            float c1 = (d1 < 1.0f) ? 0.5f * d1 * d1 : d1 - 0.5f;
            float c2 = (d2 < 1.0f) ? 0.5f * d2 * d2 : d2 - 0.5f;
            curvv = c1 + c2;
        }
    }

    float Smin  = block_reduce_sum(smin,  red, tid);
    float Smax  = block_reduce_sum(smax,  red, tid);
    float Ssym  = block_reduce_sum(symv,  red, tid);
    float Stan  = block_reduce_sum(tanv,  red, tid);
    float Scurv = block_reduce_sum(curvv, red, tid);

    if (tid == 0) {
        float overlap = 1.0f - Smin / (Smax + 1e-8f);
        float sym  = Ssym * (1.0f / 64.0f);
        float tanl = 1.0f - Stan * (1.0f / 64.0f);
        float curv = Scurv * (1.0f / 124.0f);
        float cost = 5.0f * sym + 1.0f * tanl + 0.5f * curv + 2.0f * overlap;
        float e = (gtExist[b * Ng + j] > 0.5f) ? 1.0f : 0.0f;
        out[(size_t)(b * Mp + i) * Ng + j] = cost * e;
    }
}

// ---------------------------------------------------------------------------
extern "C" void kernel_launch(void* const* d_in, const int* in_sizes, int n_in,
                              void* d_out, int out_size, void* d_ws, size_t ws_size,
                              hipStream_t stream) {
    (void)in_sizes; (void)n_in; (void)out_size; (void)ws_size;
    const float* pred  = (const float*)d_in[0];   // (2,40,24,2)
    const float* gt    = (const float*)d_in[1];   // (2,24,24,2)
    const float* vis   = (const float*)d_in[2];   // (2,24,24)
    const float* exist = (const float*)d_in[3];   // (2,24)

    float* ws     = (float*)d_ws;
    float* predRS = ws;                                   // 2*40*64*2 = 10240
    float* gtRS   = predRS + (size_t)Bb * Mp * NRS * 2;   // 2*24*64*2 = 6144
    float* gtPM   = gtRS   + (size_t)Bb * Ng * NRS * 2;   // 2*24*24   = 1152
    float* pmask  = gtPM   + (size_t)Bb * Ng * NP;        // 2*40*9216 = 737280
    float* gmask  = pmask  + (size_t)Bb * Mp * HW;        // 2*24*9216 = 442368
    float* outp   = (float*)d_out;

    hipLaunchKernelGGL(k_resample, dim3(Bb * (Mp + Ng)), dim3(64), 0, stream,
                       pred, gt, vis, predRS, gtRS, gtPM);
    hipLaunchKernelGGL(k_softmask, dim3(HW / 256, Bb * (Mp + Ng)), dim3(256), 0, stream,
                       pred, gt, gtPM, pmask, gmask);
    hipLaunchKernelGGL(k_cost, dim3(Bb * Mp * Ng), dim3(256), 0, stream,
                       predRS, gtRS, pmask, gmask, exist, outp);
}